// Round 18
// baseline (448.303 us; speedup 1.0000x reference)
//
#include <hip/hip_runtime.h>

#define DIM 192
#define NTOK 64
#define NHEAD 6
#define HDIM 32
#define SCALE 0.17677669529663687f

typedef __attribute__((ext_vector_type(8))) short bf16x8;
typedef __attribute__((ext_vector_type(4))) float f32x4;

__device__ __forceinline__ ushort f2bf(float f) {
    union { float f; unsigned u; } x; x.f = f;
    unsigned r = x.u + 0x7FFFu + ((x.u >> 16) & 1u);
    return (ushort)(r >> 16);
}
__device__ __forceinline__ float bf2f(ushort h) {
    union { unsigned u; float f; } x; x.u = ((unsigned)h) << 16;
    return x.f;
}

__device__ __forceinline__ f32x4 MF(bf16x8 a, bf16x8 b, f32x4 c) {
    return __builtin_amdgcn_mfma_f32_16x16x32_bf16(a, b, c, 0, 0, 0);
}

// A/B fragment load for 16x16x32 bf16 mfma from a row-major bf16 matrix.
// row -> lane&15 ; k -> (lane>>4)*8 + j (8 contiguous bf16 = 16B load)
__device__ __forceinline__ bf16x8 frag(const ushort* base, int stride, int r0, int k0) {
    const int l = threadIdx.x & 63;
    return *(const bf16x8*)(base + (r0 + (l & 15)) * stride + (k0 + ((l >> 4) << 3)));
}

// merged prep: blocks 0..575 convert weights; blocks 576.. build cmb table
__global__ void prep_all(const float* __restrict__ qw, const float* __restrict__ kvw,
                         const float* __restrict__ pw, const float* __restrict__ rpb,
                         const float* __restrict__ mask, ushort* __restrict__ wbf,
                         ushort* __restrict__ cmb) {
    if (blockIdx.x < 576) {
        int i = blockIdx.x * 256 + threadIdx.x;
        if (i < 36864) wbf[i] = f2bf(qw[i]);
        else if (i < 110592) wbf[i] = f2bf(kvw[i - 36864]);
        else if (i < 147456) wbf[i] = f2bf(pw[i - 110592]);
    } else {
        int t = (blockIdx.x - 576) * 256 + threadIdx.x;
        int e = t << 2;
        int n0 = e & 63;
        int m  = (e >> 6) & 63;
        int hw = e >> 12;
        int h = hw % 6, w = hw / 6;
#pragma unroll
        for (int j = 0; j < 4; ++j) {
            int n = n0 + j;
            int ridx = ((n >> 3) - (m >> 3) + 7) * 15 + ((n & 7) - (m & 7) + 7);
            float v = rpb[ridx * 6 + h] + mask[(w * 64 + n) * 64 + m];
            cmb[e + j] = f2bf(v);
        }
    }
}

// ---------------- Kernel A: projections -> fragment-linear Q/K/V (R16) ----------
// Explicit lgkmcnt drains removed: LDS ops complete in-order per wave and the
// compiler inserts counted waits before dependent uses.
__global__ __launch_bounds__(256, 4) void proj7(
    const float* __restrict__ x1, const float* __restrict__ x2,
    const float* __restrict__ qb, const float* __restrict__ kvb,
    const ushort* __restrict__ qwbf, const ushort* __restrict__ kvwbf,
    ushort* __restrict__ Qf, ushort* __restrict__ Kf, ushort* __restrict__ Vf)
{
    __shared__ __align__(16) ushort sXA[64 * 200];   // 25600 B
    __shared__ __align__(16) ushort stg[4 * 1280];   // 10240 B (per-wave [32][40])
    const int tid = threadIdx.x, wave = tid >> 6, lane = tid & 63;
    const int g = lane >> 4, mcol = lane & 15;
    const int b = blockIdx.x;
    const f32x4 zero4 = {0.f, 0.f, 0.f, 0.f};
    ushort* st = stg + wave * 1280;

    // stage x2 -> LDS bf16
    {
        const float4* src = (const float4*)(x2 + (size_t)b * 12288);
        for (int i = tid; i < 3072; i += 256) {
            float4 v = src[i];
            int e = i << 2; int n = e / DIM; int c = e - n * DIM;
            ushort4 w;
            ((ushort*)&w)[0] = f2bf(v.x); ((ushort*)&w)[1] = f2bf(v.y);
            ((ushort*)&w)[2] = f2bf(v.z); ((ushort*)&w)[3] = f2bf(v.w);
            *(ushort4*)(&sXA[n * 200 + c]) = w;
        }
    }
    __syncthreads();

    // 12 K/V head-tiles, 3 per wave
    for (int t = wave; t < 12; t += 4) {
        const int isV = (t >= 6) ? 1 : 0;
        const int h = isV ? (t - 6) : t;
        bf16x8 wf[2][6];
#pragma unroll
        for (int c2 = 0; c2 < 2; ++c2) {
            int ctg = (isV ? (12 + 2 * h) : (2 * h)) + c2;
#pragma unroll
            for (int ks = 0; ks < 6; ++ks)
                wf[c2][ks] = frag(kvwbf, DIM, ctg * 16, ks * 32);
        }
        f32x4 acc[4][2];
#pragma unroll
        for (int rt = 0; rt < 4; ++rt)
#pragma unroll
            for (int c2 = 0; c2 < 2; ++c2) acc[rt][c2] = zero4;
#pragma unroll
        for (int rt = 0; rt < 4; ++rt) {
            bf16x8 af[6];
#pragma unroll
            for (int ks = 0; ks < 6; ++ks) af[ks] = frag(sXA, 200, rt * 16, ks * 32);
#pragma unroll
            for (int c2 = 0; c2 < 2; ++c2)
#pragma unroll
                for (int ks = 0; ks < 6; ++ks)
                    acc[rt][c2] = MF(af[ks], wf[c2][ks], acc[rt][c2]);
        }
        if (!isV) {                 // K: two phases of 32 rows
#pragma unroll
            for (int ph = 0; ph < 2; ++ph) {
#pragma unroll
                for (int c2 = 0; c2 < 2; ++c2) {
                    float bv = kvb[h * 32 + c2 * 16 + mcol];
#pragma unroll
                    for (int rl = 0; rl < 2; ++rl)
#pragma unroll
                        for (int j = 0; j < 4; ++j)
                            st[(rl * 16 + (g << 2) + j) * 40 + c2 * 16 + mcol] =
                                f2bf(acc[2 * ph + rl][c2][j] + bv);
                }
#pragma unroll
                for (int cl = 0; cl < 2; ++cl) {
                    bf16x8 fr = frag(st, 40, cl * 16, 0);
                    *(bf16x8*)(Kf + ((size_t)(b * 6 + h) * 4 + 2 * ph + cl) * 512 + lane * 8) = fr;
                }
            }
        } else {                    // V: two phases of 32 m-cols, staged [32 d][40 m]
#pragma unroll
            for (int c = 0; c < 2; ++c) {
#pragma unroll
                for (int c2 = 0; c2 < 2; ++c2) {
                    float bv = kvb[192 + h * 32 + c2 * 16 + mcol];
#pragma unroll
                    for (int rl = 0; rl < 2; ++rl) {
                        ushort4 w4;
#pragma unroll
                        for (int j = 0; j < 4; ++j)
                            ((ushort*)&w4)[j] = f2bf(acc[2 * c + rl][c2][j] + bv);
                        *(ushort4*)(&st[(c2 * 16 + mcol) * 40 + rl * 16 + (g << 2)]) = w4;
                    }
                }
#pragma unroll
                for (int ctd = 0; ctd < 2; ++ctd) {
                    bf16x8 fr = frag(st, 40, ctd * 16, 0);
                    *(bf16x8*)(Vf + (((size_t)(b * 6 + h) * 2 + c) * 2 + ctd) * 512 + lane * 8) = fr;
                }
            }
        }
    }
    __syncthreads();

    // stage x1 -> LDS bf16
    {
        const float4* src = (const float4*)(x1 + (size_t)b * 12288);
        for (int i = tid; i < 3072; i += 256) {
            float4 v = src[i];
            int e = i << 2; int n = e / DIM; int c = e - n * DIM;
            ushort4 w;
            ((ushort*)&w)[0] = f2bf(v.x); ((ushort*)&w)[1] = f2bf(v.y);
            ((ushort*)&w)[2] = f2bf(v.z); ((ushort*)&w)[3] = f2bf(v.w);
            *(ushort4*)(&sXA[n * 200 + c]) = w;
        }
    }
    __syncthreads();

    // 6 Q head-tiles
    for (int t = wave; t < 6; t += 4) {
        const int h = t;
        bf16x8 wf[2][6];
#pragma unroll
        for (int c2 = 0; c2 < 2; ++c2)
#pragma unroll
            for (int ks = 0; ks < 6; ++ks)
                wf[c2][ks] = frag(qwbf, DIM, (2 * h + c2) * 16, ks * 32);
        f32x4 acc[4][2];
#pragma unroll
        for (int rt = 0; rt < 4; ++rt)
#pragma unroll
            for (int c2 = 0; c2 < 2; ++c2) acc[rt][c2] = zero4;
#pragma unroll
        for (int rt = 0; rt < 4; ++rt) {
            bf16x8 af[6];
#pragma unroll
            for (int ks = 0; ks < 6; ++ks) af[ks] = frag(sXA, 200, rt * 16, ks * 32);
#pragma unroll
            for (int c2 = 0; c2 < 2; ++c2)
#pragma unroll
                for (int ks = 0; ks < 6; ++ks)
                    acc[rt][c2] = MF(af[ks], wf[c2][ks], acc[rt][c2]);
        }
#pragma unroll
        for (int ph = 0; ph < 2; ++ph) {
#pragma unroll
            for (int c2 = 0; c2 < 2; ++c2) {
                float bv = qb[h * 32 + c2 * 16 + mcol];
#pragma unroll
                for (int rl = 0; rl < 2; ++rl)
#pragma unroll
                    for (int j = 0; j < 4; ++j)
                        st[(rl * 16 + (g << 2) + j) * 40 + c2 * 16 + mcol] =
                            f2bf((acc[2 * ph + rl][c2][j] + bv) * SCALE);
            }
#pragma unroll
            for (int cl = 0; cl < 2; ++cl) {
                bf16x8 fr = frag(st, 40, cl * 16, 0);
                *(bf16x8*)(Qf + ((size_t)(b * 6 + h) * 4 + 2 * ph + cl) * 512 + lane * 8) = fr;
            }
        }
    }
}

// ---------------- Kernel B1: attention, 1 wave per (window,head), no barriers ----
// Y [d][n] (32x64 bf16) overwrites the dead Kf slot of the same (window,head).
__global__ __launch_bounds__(256, 4) void attn_heads(
    const ushort* __restrict__ Qf, ushort* KfY,
    const ushort* __restrict__ Vf, const ushort* __restrict__ cmb)
{
    __shared__ __align__(16) ushort sP[4 * 1280];   // per-wave P slice [16][72]
    const int tid = threadIdx.x, wave = tid >> 6, lane = tid & 63;
    const int g = lane >> 4, mcol = lane & 15;
    const int gid = blockIdx.x * 4 + wave;          // 0..12287
    const int w = gid / 6, h = gid - 6 * (gid / 6);
    const f32x4 zero4 = {0.f, 0.f, 0.f, 0.f};

    const ushort* qp = Qf  + (size_t)gid * 2048;
    ushort*       kp = KfY + (size_t)gid * 2048;
    const ushort* vp = Vf  + (size_t)gid * 2048;
    const ushort* cp = cmb + (size_t)((w & 63) * 6 + h) * 4096;
    ushort* slot = sP + wave * 1280;

    bf16x8 kb[4], vb[4];
#pragma unroll
    for (int ct = 0; ct < 4; ++ct) kb[ct] = *(const bf16x8*)(kp + ct * 512 + lane * 8);
#pragma unroll
    for (int c = 0; c < 4; ++c) vb[c] = *(const bf16x8*)(vp + c * 512 + lane * 8);

    ushort4 y4[4][2];
#pragma unroll
    for (int rt = 0; rt < 4; ++rt) {
        bf16x8 qa = *(const bf16x8*)(qp + rt * 512 + lane * 8);
        f32x4 acc[4];
#pragma unroll
        for (int ct = 0; ct < 4; ++ct) acc[ct] = MF(qa, kb[ct], zero4);
#pragma unroll
        for (int ct = 0; ct < 4; ++ct) {
            ushort4 b4 = *(const ushort4*)(cp + (ct * 16 + mcol) * 64 + rt * 16 + (g << 2));
#pragma unroll
            for (int j = 0; j < 4; ++j) acc[ct][j] += bf2f(((ushort*)&b4)[j]);
        }
        float sm[4];
#pragma unroll
        for (int j = 0; j < 4; ++j) {
            float v = fmaxf(fmaxf(acc[0][j], acc[1][j]), fmaxf(acc[2][j], acc[3][j]));
            v = fmaxf(v, __shfl_xor(v, 1, 64));
            v = fmaxf(v, __shfl_xor(v, 2, 64));
            v = fmaxf(v, __shfl_xor(v, 4, 64));
            v = fmaxf(v, __shfl_xor(v, 8, 64));
            float s = 0.f;
#pragma unroll
            for (int ct = 0; ct < 4; ++ct) {
                float p = __expf(acc[ct][j] - v);
                acc[ct][j] = p; s += p;
            }
            s += __shfl_xor(s, 1, 64);
            s += __shfl_xor(s, 2, 64);
            s += __shfl_xor(s, 4, 64);
            s += __shfl_xor(s, 8, 64);
            sm[j] = 1.0f / s;
        }
#pragma unroll
        for (int ct = 0; ct < 4; ++ct)
#pragma unroll
            for (int j = 0; j < 4; ++j)
                slot[((g << 2) + j) * 72 + ct * 16 + mcol] = f2bf(acc[ct][j] * sm[j]);
        f32x4 ay0 = zero4, ay1 = zero4;
#pragma unroll
        for (int c = 0; c < 2; ++c) {
            bf16x8 pa = frag(slot, 72, 0, c * 32);
            ay0 = MF(pa, vb[c * 2 + 0], ay0);
            ay1 = MF(pa, vb[c * 2 + 1], ay1);
        }
#pragma unroll
        for (int j = 0; j < 4; ++j) {
            ((ushort*)&y4[rt][0])[j] = f2bf(ay0[j]);
            ((ushort*)&y4[rt][1])[j] = f2bf(ay1[j]);
        }
    }
    // write Y [d][n] over dead Kf slot (all kp reads completed above)
#pragma unroll
    for (int rt = 0; rt < 4; ++rt)
#pragma unroll
        for (int ctd = 0; ctd < 2; ++ctd)
            *(ushort4*)(kp + (ctd * 16 + mcol) * 64 + rt * 16 + (g << 2)) = y4[rt][ctd];
}

// ---------------- Kernel B2: LAM + residual + output projection (R16) -----------
__global__ __launch_bounds__(256, 4) void lam_proj(
    const ushort* __restrict__ Yd, const ushort* __restrict__ Qf,
    const float* __restrict__ x1, const float* __restrict__ gammap,
    const ushort* __restrict__ pwbf, const float* __restrict__ pb,
    float* __restrict__ out)
{
    __shared__ __align__(16) ushort sYF[13824];   // Y [6][32][72] ; later finalX [64][200]
    __shared__ __align__(16) float  sE[32 * 33];
    __shared__ __align__(16) ushort sAtt[32 * 40];

    const int tid = threadIdx.x, wave = tid >> 6, lane = tid & 63;
    const int g = lane >> 4, mcol = lane & 15;
    const int b = blockIdx.x;
    const float gamma = gammap[0];
    const f32x4 zero4 = {0.f, 0.f, 0.f, 0.f};

    // coop load Yd (6 heads x [32][64] ushort) -> LDS [6][32][72], 16B granules
    {
        const ushort* src = Yd + (size_t)b * 12288;
        for (int i = tid; i < 1536; i += 256) {
            int hd = i >> 8;
            int rem = i & 255;
            int row = rem >> 3, k8 = rem & 7;
            uint4 v = *(const uint4*)(src + hd * 2048 + row * 64 + k8 * 8);
            *(uint4*)(&sYF[hd * 2304 + row * 72 + k8 * 8]) = v;
        }
    }
    __syncthreads();

    // energy = flat @ flat^T [32x32], K=384; 4 waves, one 16x16 tile each
    {
        int rt = wave >> 1, ct = wave & 1;
        f32x4 a0 = zero4, a1 = zero4;
#pragma unroll
        for (int hd = 0; hd < 6; hd += 2) {
            const ushort* Y0 = sYF + hd * 2304;
            const ushort* Y1 = sYF + (hd + 1) * 2304;
#pragma unroll
            for (int kk = 0; kk < 2; ++kk) {
                a0 = MF(frag(Y0, 72, rt * 16, kk * 32), frag(Y0, 72, ct * 16, kk * 32), a0);
                a1 = MF(frag(Y1, 72, rt * 16, kk * 32), frag(Y1, 72, ct * 16, kk * 32), a1);
            }
        }
        f32x4 acc = a0 + a1;
#pragma unroll
        for (int j = 0; j < 4; ++j)
            sE[(rt * 16 + (g << 2) + j) * 33 + ct * 16 + mcol] = acc[j];
    }
    __syncthreads();

    // softmax rows of energy -> att bf16 (32 rows x 8 lanes)
    {
        int r = tid >> 3, l8 = tid & 7;
        float e[4];
        float mx = -1e30f;
#pragma unroll
        for (int k = 0; k < 4; ++k) { e[k] = sE[r * 33 + l8 + k * 8]; mx = fmaxf(mx, e[k]); }
        mx = fmaxf(mx, __shfl_xor(mx, 1, 64));
        mx = fmaxf(mx, __shfl_xor(mx, 2, 64));
        mx = fmaxf(mx, __shfl_xor(mx, 4, 64));
        float s = 0.f;
#pragma unroll
        for (int k = 0; k < 4; ++k) { e[k] = __expf(e[k] - mx); s += e[k]; }
        s += __shfl_xor(s, 1, 64);
        s += __shfl_xor(s, 2, 64);
        s += __shfl_xor(s, 4, 64);
        float rs = 1.0f / s;
#pragma unroll
        for (int k = 0; k < 4; ++k) sAtt[r * 40 + l8 + k * 8] = f2bf(e[k] * rs);
    }
    __syncthreads();

    // outm = att @ flat ; finalX = gamma*outm + flat + (q̂ + x1)
    bf16x8 aa01[2];
    aa01[0] = frag(sAtt, 40, 0, 0);
    aa01[1] = frag(sAtt, 40, 16, 0);
    ushort4 w4st[12];
#pragma unroll
    for (int i = 0; i < 12; ++i) {
        int t = wave + i * 4;
        int rtL = t & 1, ct = t >> 1;
        int col = ct * 16 + mcol;
        int hh = col >> 6, nn = col & 63;
        const ushort* Yh = sYF + hh * 2304;
        bf16x8 bb;
#pragma unroll
        for (int jj = 0; jj < 8; ++jj) bb[jj] = (short)Yh[((g << 3) + jj) * 72 + nn];
        f32x4 acc = MF(aa01[rtL], bb, zero4);
        int d0 = rtL * 16 + (g << 2);
        ushort4 qv4 = *(const ushort4*)(Qf + (size_t)(b * 6 + hh) * 2048 +
                                        (nn >> 4) * 512 + ((nn & 15) + ((d0 >> 3) << 4)) * 8 + (d0 & 7));
        float4 xv4 = *(const float4*)(x1 + (size_t)b * 12288 + nn * 192 + hh * 32 + d0);
        ushort4 w4;
#pragma unroll
        for (int j = 0; j < 4; ++j) {
            float flatv = bf2f(Yh[(d0 + j) * 72 + nn]);
            float val = gamma * acc[j] + flatv + bf2f(((ushort*)&qv4)[j]) + ((const float*)&xv4)[j];
            ((ushort*)&w4)[j] = f2bf(val);
        }
        w4st[i] = w4;
    }
    __syncthreads();
#pragma unroll
    for (int i = 0; i < 12; ++i) {
        int t = wave + i * 4;
        int rtL = t & 1, ct = t >> 1;
        int col = ct * 16 + mcol;
        int hh = col >> 6, nn = col & 63;
        int d0 = rtL * 16 + (g << 2);
        *(ushort4*)(&sYF[nn * 200 + hh * 32 + d0]) = w4st[i];
    }
    __syncthreads();

    // out = finalX @ pw^T + pb ; ct-major: each wave owns 3 col-tiles, pw frags
    // register-resident per ct
    {
        float* outp = out + (size_t)b * 12288;
#pragma unroll
        for (int q = 0; q < 3; ++q) {
            int ct = wave * 3 + q;
            bf16x8 wfp[6];
#pragma unroll
            for (int ks = 0; ks < 6; ++ks) wfp[ks] = frag(pwbf, DIM, ct * 16, ks * 32);
            int co = ct * 16 + mcol;
            float pbv = pb[co];
#pragma unroll
            for (int rt = 0; rt < 4; ++rt) {
                f32x4 acc = zero4;
#pragma unroll
                for (int ks = 0; ks < 6; ++ks)
                    acc = MF(frag(sYF, 200, rt * 16, ks * 32), wfp[ks], acc);
#pragma unroll
                for (int j = 0; j < 4; ++j)
                    outp[(rt * 16 + (g << 2) + j) * DIM + co] = acc[j] + pbv;
            }
        }
    }
}

extern "C" void kernel_launch(void* const* d_in, const int* in_sizes, int n_in,
                              void* d_out, int out_size, void* d_ws, size_t ws_size,
                              hipStream_t stream) {
    const float* x1    = (const float*)d_in[0];
    const float* x2    = (const float*)d_in[1];
    const float* mask  = (const float*)d_in[2];
    const float* qw    = (const float*)d_in[3];
    const float* qbv   = (const float*)d_in[4];
    const float* kvw   = (const float*)d_in[5];
    const float* kvbv  = (const float*)d_in[6];
    const float* rpb   = (const float*)d_in[7];
    const float* gamma = (const float*)d_in[8];
    const float* pw    = (const float*)d_in[9];
    const float* pbv   = (const float*)d_in[10];
    ushort* wbf = (ushort*)d_ws;     // qw_bf | kvw_bf | pw_bf

    ushort* cmb = wbf + 147456;      // 3 MB bias+mask table
    ushort* Qf  = wbf + 1720320;     // fragment-linear q̂ (pre-scaled)
    ushort* Kf  = wbf + 26886144;    // fragment-linear K; becomes Y after attn
    ushort* Vf  = wbf + 52051968;    // fragment-linear V

    prep_all<<<2112, 256, 0, stream>>>(qw, kvw, pw, rpb, mask, wbf, cmb);
    proj7<<<2048, 256, 0, stream>>>(x1, x2, qbv, kvbv,
                                    wbf, wbf + 36864, Qf, Kf, Vf);
    attn_heads<<<3072, 256, 0, stream>>>(Qf, Kf, Vf, cmb);
    lam_proj<<<2048, 256, 0, stream>>>(Kf, Qf, x1, gamma,
                                       wbf + 110592, pbv, (float*)d_out);
}

// Round 19
// 241.979 us; speedup vs baseline: 1.8527x; 1.8527x over previous
//
#include <hip/hip_runtime.h>

#define DIM 192
#define NTOK 64
#define NHEAD 6
#define HDIM 32
#define SCALE 0.17677669529663687f

typedef __attribute__((ext_vector_type(8))) short bf16x8;
typedef __attribute__((ext_vector_type(4))) float f32x4;

__device__ __forceinline__ ushort f2bf(float f) {
    union { float f; unsigned u; } x; x.f = f;
    unsigned r = x.u + 0x7FFFu + ((x.u >> 16) & 1u);
    return (ushort)(r >> 16);
}
__device__ __forceinline__ float bf2f(ushort h) {
    union { unsigned u; float f; } x; x.u = ((unsigned)h) << 16;
    return x.f;
}

__device__ __forceinline__ f32x4 MF(bf16x8 a, bf16x8 b, f32x4 c) {
    return __builtin_amdgcn_mfma_f32_16x16x32_bf16(a, b, c, 0, 0, 0);
}

// A/B fragment load for 16x16x32 bf16 mfma from a row-major bf16 matrix.
// row -> lane&15 ; k -> (lane>>4)*8 + j (8 contiguous bf16 = 16B load)
__device__ __forceinline__ bf16x8 frag(const ushort* base, int stride, int r0, int k0) {
    const int l = threadIdx.x & 63;
    return *(const bf16x8*)(base + (r0 + (l & 15)) * stride + (k0 + ((l >> 4) << 3)));
}

// merged prep: blocks 0..575 convert weights; blocks 576.. build cmb table
__global__ void prep_all(const float* __restrict__ qw, const float* __restrict__ kvw,
                         const float* __restrict__ pw, const float* __restrict__ rpb,
                         const float* __restrict__ mask, ushort* __restrict__ wbf,
                         ushort* __restrict__ cmb) {
    if (blockIdx.x < 576) {
        int i = blockIdx.x * 256 + threadIdx.x;
        if (i < 36864) wbf[i] = f2bf(qw[i]);
        else if (i < 110592) wbf[i] = f2bf(kvw[i - 36864]);
        else if (i < 147456) wbf[i] = f2bf(pw[i - 110592]);
    } else {
        int t = (blockIdx.x - 576) * 256 + threadIdx.x;
        int e = t << 2;
        int n0 = e & 63;
        int m  = (e >> 6) & 63;
        int hw = e >> 12;
        int h = hw % 6, w = hw / 6;
#pragma unroll
        for (int j = 0; j < 4; ++j) {
            int n = n0 + j;
            int ridx = ((n >> 3) - (m >> 3) + 7) * 15 + ((n & 7) - (m & 7) + 7);
            float v = rpb[ridx * 6 + h] + mask[(w * 64 + n) * 64 + m];
            cmb[e + j] = f2bf(v);
        }
    }
}

// ---------------- Kernel A: projections -> fragment-linear Q/K/V (R16 best) -----
// Two-phase epilogues; WAR drains removed, RAW drains kept (load-bearing: they
// pin a schedule the allocator handles without scratch — see R18 regression).
__global__ __launch_bounds__(256, 4) void proj7(
    const float* __restrict__ x1, const float* __restrict__ x2,
    const float* __restrict__ qb, const float* __restrict__ kvb,
    const ushort* __restrict__ qwbf, const ushort* __restrict__ kvwbf,
    ushort* __restrict__ Qf, ushort* __restrict__ Kf, ushort* __restrict__ Vf)
{
    __shared__ __align__(16) ushort sXA[64 * 200];   // 25600 B
    __shared__ __align__(16) ushort stg[4 * 1280];   // 10240 B (per-wave [32][40])
    const int tid = threadIdx.x, wave = tid >> 6, lane = tid & 63;
    const int g = lane >> 4, mcol = lane & 15;
    const int b = blockIdx.x;
    const f32x4 zero4 = {0.f, 0.f, 0.f, 0.f};
    ushort* st = stg + wave * 1280;

    // stage x2 -> LDS bf16
    {
        const float4* src = (const float4*)(x2 + (size_t)b * 12288);
        for (int i = tid; i < 3072; i += 256) {
            float4 v = src[i];
            int e = i << 2; int n = e / DIM; int c = e - n * DIM;
            ushort4 w;
            ((ushort*)&w)[0] = f2bf(v.x); ((ushort*)&w)[1] = f2bf(v.y);
            ((ushort*)&w)[2] = f2bf(v.z); ((ushort*)&w)[3] = f2bf(v.w);
            *(ushort4*)(&sXA[n * 200 + c]) = w;
        }
    }
    __syncthreads();

    // 12 K/V head-tiles, 3 per wave
    for (int t = wave; t < 12; t += 4) {
        const int isV = (t >= 6) ? 1 : 0;
        const int h = isV ? (t - 6) : t;
        bf16x8 wf[2][6];
#pragma unroll
        for (int c2 = 0; c2 < 2; ++c2) {
            int ctg = (isV ? (12 + 2 * h) : (2 * h)) + c2;
#pragma unroll
            for (int ks = 0; ks < 6; ++ks)
                wf[c2][ks] = frag(kvwbf, DIM, ctg * 16, ks * 32);
        }
        f32x4 acc[4][2];
#pragma unroll
        for (int rt = 0; rt < 4; ++rt)
#pragma unroll
            for (int c2 = 0; c2 < 2; ++c2) acc[rt][c2] = zero4;
#pragma unroll
        for (int rt = 0; rt < 4; ++rt) {
            bf16x8 af[6];
#pragma unroll
            for (int ks = 0; ks < 6; ++ks) af[ks] = frag(sXA, 200, rt * 16, ks * 32);
#pragma unroll
            for (int c2 = 0; c2 < 2; ++c2)
#pragma unroll
                for (int ks = 0; ks < 6; ++ks)
                    acc[rt][c2] = MF(af[ks], wf[c2][ks], acc[rt][c2]);
        }
        if (!isV) {                 // K: two phases of 32 rows
#pragma unroll
            for (int ph = 0; ph < 2; ++ph) {
#pragma unroll
                for (int c2 = 0; c2 < 2; ++c2) {
                    float bv = kvb[h * 32 + c2 * 16 + mcol];
#pragma unroll
                    for (int rl = 0; rl < 2; ++rl)
#pragma unroll
                        for (int j = 0; j < 4; ++j)
                            st[(rl * 16 + (g << 2) + j) * 40 + c2 * 16 + mcol] =
                                f2bf(acc[2 * ph + rl][c2][j] + bv);
                }
                asm volatile("s_waitcnt lgkmcnt(0)" ::: "memory");
#pragma unroll
                for (int cl = 0; cl < 2; ++cl) {
                    bf16x8 fr = frag(st, 40, cl * 16, 0);
                    *(bf16x8*)(Kf + ((size_t)(b * 6 + h) * 4 + 2 * ph + cl) * 512 + lane * 8) = fr;
                }
            }
        } else {                    // V: two phases of 32 m-cols, staged [32 d][40 m]
#pragma unroll
            for (int c = 0; c < 2; ++c) {
#pragma unroll
                for (int c2 = 0; c2 < 2; ++c2) {
                    float bv = kvb[192 + h * 32 + c2 * 16 + mcol];
#pragma unroll
                    for (int rl = 0; rl < 2; ++rl) {
                        ushort4 w4;
#pragma unroll
                        for (int j = 0; j < 4; ++j)
                            ((ushort*)&w4)[j] = f2bf(acc[2 * c + rl][c2][j] + bv);
                        *(ushort4*)(&st[(c2 * 16 + mcol) * 40 + rl * 16 + (g << 2)]) = w4;
                    }
                }
                asm volatile("s_waitcnt lgkmcnt(0)" ::: "memory");
#pragma unroll
                for (int ctd = 0; ctd < 2; ++ctd) {
                    bf16x8 fr = frag(st, 40, ctd * 16, 0);
                    *(bf16x8*)(Vf + (((size_t)(b * 6 + h) * 2 + c) * 2 + ctd) * 512 + lane * 8) = fr;
                }
            }
        }
    }
    __syncthreads();

    // stage x1 -> LDS bf16
    {
        const float4* src = (const float4*)(x1 + (size_t)b * 12288);
        for (int i = tid; i < 3072; i += 256) {
            float4 v = src[i];
            int e = i << 2; int n = e / DIM; int c = e - n * DIM;
            ushort4 w;
            ((ushort*)&w)[0] = f2bf(v.x); ((ushort*)&w)[1] = f2bf(v.y);
            ((ushort*)&w)[2] = f2bf(v.z); ((ushort*)&w)[3] = f2bf(v.w);
            *(ushort4*)(&sXA[n * 200 + c]) = w;
        }
    }
    __syncthreads();

    // 6 Q head-tiles
    for (int t = wave; t < 6; t += 4) {
        const int h = t;
        bf16x8 wf[2][6];
#pragma unroll
        for (int c2 = 0; c2 < 2; ++c2)
#pragma unroll
            for (int ks = 0; ks < 6; ++ks)
                wf[c2][ks] = frag(qwbf, DIM, (2 * h + c2) * 16, ks * 32);
        f32x4 acc[4][2];
#pragma unroll
        for (int rt = 0; rt < 4; ++rt)
#pragma unroll
            for (int c2 = 0; c2 < 2; ++c2) acc[rt][c2] = zero4;
#pragma unroll
        for (int rt = 0; rt < 4; ++rt) {
            bf16x8 af[6];
#pragma unroll
            for (int ks = 0; ks < 6; ++ks) af[ks] = frag(sXA, 200, rt * 16, ks * 32);
#pragma unroll
            for (int c2 = 0; c2 < 2; ++c2)
#pragma unroll
                for (int ks = 0; ks < 6; ++ks)
                    acc[rt][c2] = MF(af[ks], wf[c2][ks], acc[rt][c2]);
        }
#pragma unroll
        for (int ph = 0; ph < 2; ++ph) {
#pragma unroll
            for (int c2 = 0; c2 < 2; ++c2) {
                float bv = qb[h * 32 + c2 * 16 + mcol];
#pragma unroll
                for (int rl = 0; rl < 2; ++rl)
#pragma unroll
                    for (int j = 0; j < 4; ++j)
                        st[(rl * 16 + (g << 2) + j) * 40 + c2 * 16 + mcol] =
                            f2bf((acc[2 * ph + rl][c2][j] + bv) * SCALE);
            }
            asm volatile("s_waitcnt lgkmcnt(0)" ::: "memory");
#pragma unroll
            for (int cl = 0; cl < 2; ++cl) {
                bf16x8 fr = frag(st, 40, cl * 16, 0);
                *(bf16x8*)(Qf + ((size_t)(b * 6 + h) * 4 + 2 * ph + cl) * 512 + lane * 8) = fr;
            }
        }
    }
}

// ---------------- Kernel B1: attention, 1 wave per (window,head), no barriers ----
// Y [d][n] (32x64 bf16) overwrites the dead Kf slot of the same (window,head).
__global__ __launch_bounds__(256, 4) void attn_heads(
    const ushort* __restrict__ Qf, ushort* KfY,
    const ushort* __restrict__ Vf, const ushort* __restrict__ cmb)
{
    __shared__ __align__(16) ushort sP[4 * 1280];   // per-wave P slice [16][72]
    const int tid = threadIdx.x, wave = tid >> 6, lane = tid & 63;
    const int g = lane >> 4, mcol = lane & 15;
    const int gid = blockIdx.x * 4 + wave;          // 0..12287
    const int w = gid / 6, h = gid - 6 * (gid / 6);
    const f32x4 zero4 = {0.f, 0.f, 0.f, 0.f};

    const ushort* qp = Qf  + (size_t)gid * 2048;
    ushort*       kp = KfY + (size_t)gid * 2048;
    const ushort* vp = Vf  + (size_t)gid * 2048;
    const ushort* cp = cmb + (size_t)((w & 63) * 6 + h) * 4096;
    ushort* slot = sP + wave * 1280;

    bf16x8 kb[4], vb[4];
#pragma unroll
    for (int ct = 0; ct < 4; ++ct) kb[ct] = *(const bf16x8*)(kp + ct * 512 + lane * 8);
#pragma unroll
    for (int c = 0; c < 4; ++c) vb[c] = *(const bf16x8*)(vp + c * 512 + lane * 8);

    ushort4 y4[4][2];
#pragma unroll
    for (int rt = 0; rt < 4; ++rt) {
        bf16x8 qa = *(const bf16x8*)(qp + rt * 512 + lane * 8);
        f32x4 acc[4];
#pragma unroll
        for (int ct = 0; ct < 4; ++ct) acc[ct] = MF(qa, kb[ct], zero4);
#pragma unroll
        for (int ct = 0; ct < 4; ++ct) {
            ushort4 b4 = *(const ushort4*)(cp + (ct * 16 + mcol) * 64 + rt * 16 + (g << 2));
#pragma unroll
            for (int j = 0; j < 4; ++j) acc[ct][j] += bf2f(((ushort*)&b4)[j]);
        }
        float sm[4];
#pragma unroll
        for (int j = 0; j < 4; ++j) {
            float v = fmaxf(fmaxf(acc[0][j], acc[1][j]), fmaxf(acc[2][j], acc[3][j]));
            v = fmaxf(v, __shfl_xor(v, 1, 64));
            v = fmaxf(v, __shfl_xor(v, 2, 64));
            v = fmaxf(v, __shfl_xor(v, 4, 64));
            v = fmaxf(v, __shfl_xor(v, 8, 64));
            float s = 0.f;
#pragma unroll
            for (int ct = 0; ct < 4; ++ct) {
                float p = __expf(acc[ct][j] - v);
                acc[ct][j] = p; s += p;
            }
            s += __shfl_xor(s, 1, 64);
            s += __shfl_xor(s, 2, 64);
            s += __shfl_xor(s, 4, 64);
            s += __shfl_xor(s, 8, 64);
            sm[j] = 1.0f / s;
        }
#pragma unroll
        for (int ct = 0; ct < 4; ++ct)
#pragma unroll
            for (int j = 0; j < 4; ++j)
                slot[((g << 2) + j) * 72 + ct * 16 + mcol] = f2bf(acc[ct][j] * sm[j]);
        asm volatile("s_waitcnt lgkmcnt(0)" ::: "memory");
        f32x4 ay0 = zero4, ay1 = zero4;
#pragma unroll
        for (int c = 0; c < 2; ++c) {
            bf16x8 pa = frag(slot, 72, 0, c * 32);
            ay0 = MF(pa, vb[c * 2 + 0], ay0);
            ay1 = MF(pa, vb[c * 2 + 1], ay1);
        }
#pragma unroll
        for (int j = 0; j < 4; ++j) {
            ((ushort*)&y4[rt][0])[j] = f2bf(ay0[j]);
            ((ushort*)&y4[rt][1])[j] = f2bf(ay1[j]);
        }
    }
    // write Y [d][n] over dead Kf slot (all kp reads completed above)
#pragma unroll
    for (int rt = 0; rt < 4; ++rt)
#pragma unroll
        for (int ctd = 0; ctd < 2; ++ctd)
            *(ushort4*)(kp + (ctd * 16 + mcol) * 64 + rt * 16 + (g << 2)) = y4[rt][ctd];
}

// ---------------- Kernel B2: LAM + residual + output projection (R16) -----------
__global__ __launch_bounds__(256, 4) void lam_proj(
    const ushort* __restrict__ Yd, const ushort* __restrict__ Qf,
    const float* __restrict__ x1, const float* __restrict__ gammap,
    const ushort* __restrict__ pwbf, const float* __restrict__ pb,
    float* __restrict__ out)
{
    __shared__ __align__(16) ushort sYF[13824];   // Y [6][32][72] ; later finalX [64][200]
    __shared__ __align__(16) float  sE[32 * 33];
    __shared__ __align__(16) ushort sAtt[32 * 40];

    const int tid = threadIdx.x, wave = tid >> 6, lane = tid & 63;
    const int g = lane >> 4, mcol = lane & 15;
    const int b = blockIdx.x;
    const float gamma = gammap[0];
    const f32x4 zero4 = {0.f, 0.f, 0.f, 0.f};

    // coop load Yd (6 heads x [32][64] ushort) -> LDS [6][32][72], 16B granules
    {
        const ushort* src = Yd + (size_t)b * 12288;
        for (int i = tid; i < 1536; i += 256) {
            int hd = i >> 8;
            int rem = i & 255;
            int row = rem >> 3, k8 = rem & 7;
            uint4 v = *(const uint4*)(src + hd * 2048 + row * 64 + k8 * 8);
            *(uint4*)(&sYF[hd * 2304 + row * 72 + k8 * 8]) = v;
        }
    }
    __syncthreads();

    // energy = flat @ flat^T [32x32], K=384; 4 waves, one 16x16 tile each
    {
        int rt = wave >> 1, ct = wave & 1;
        f32x4 a0 = zero4, a1 = zero4;
#pragma unroll
        for (int hd = 0; hd < 6; hd += 2) {
            const ushort* Y0 = sYF + hd * 2304;
            const ushort* Y1 = sYF + (hd + 1) * 2304;
#pragma unroll
            for (int kk = 0; kk < 2; ++kk) {
                a0 = MF(frag(Y0, 72, rt * 16, kk * 32), frag(Y0, 72, ct * 16, kk * 32), a0);
                a1 = MF(frag(Y1, 72, rt * 16, kk * 32), frag(Y1, 72, ct * 16, kk * 32), a1);
            }
        }
        f32x4 acc = a0 + a1;
#pragma unroll
        for (int j = 0; j < 4; ++j)
            sE[(rt * 16 + (g << 2) + j) * 33 + ct * 16 + mcol] = acc[j];
    }
    __syncthreads();

    // softmax rows of energy -> att bf16 (32 rows x 8 lanes)
    {
        int r = tid >> 3, l8 = tid & 7;
        float e[4];
        float mx = -1e30f;
#pragma unroll
        for (int k = 0; k < 4; ++k) { e[k] = sE[r * 33 + l8 + k * 8]; mx = fmaxf(mx, e[k]); }
        mx = fmaxf(mx, __shfl_xor(mx, 1, 64));
        mx = fmaxf(mx, __shfl_xor(mx, 2, 64));
        mx = fmaxf(mx, __shfl_xor(mx, 4, 64));
        float s = 0.f;
#pragma unroll
        for (int k = 0; k < 4; ++k) { e[k] = __expf(e[k] - mx); s += e[k]; }
        s += __shfl_xor(s, 1, 64);
        s += __shfl_xor(s, 2, 64);
        s += __shfl_xor(s, 4, 64);
        float rs = 1.0f / s;
#pragma unroll
        for (int k = 0; k < 4; ++k) sAtt[r * 40 + l8 + k * 8] = f2bf(e[k] * rs);
    }
    __syncthreads();

    // outm = att @ flat ; finalX = gamma*outm + flat + (q̂ + x1)
    bf16x8 aa01[2];
    aa01[0] = frag(sAtt, 40, 0, 0);
    aa01[1] = frag(sAtt, 40, 16, 0);
    ushort4 w4st[12];
#pragma unroll
    for (int i = 0; i < 12; ++i) {
        int t = wave + i * 4;
        int rtL = t & 1, ct = t >> 1;
        int col = ct * 16 + mcol;
        int hh = col >> 6, nn = col & 63;
        const ushort* Yh = sYF + hh * 2304;
        bf16x8 bb;
#pragma unroll
        for (int jj = 0; jj < 8; ++jj) bb[jj] = (short)Yh[((g << 3) + jj) * 72 + nn];
        f32x4 acc = MF(aa01[rtL], bb, zero4);
        int d0 = rtL * 16 + (g << 2);
        ushort4 qv4 = *(const ushort4*)(Qf + (size_t)(b * 6 + hh) * 2048 +
                                        (nn >> 4) * 512 + ((nn & 15) + ((d0 >> 3) << 4)) * 8 + (d0 & 7));
        float4 xv4 = *(const float4*)(x1 + (size_t)b * 12288 + nn * 192 + hh * 32 + d0);
        ushort4 w4;
#pragma unroll
        for (int j = 0; j < 4; ++j) {
            float flatv = bf2f(Yh[(d0 + j) * 72 + nn]);
            float val = gamma * acc[j] + flatv + bf2f(((ushort*)&qv4)[j]) + ((const float*)&xv4)[j];
            ((ushort*)&w4)[j] = f2bf(val);
        }
        w4st[i] = w4;
    }
    __syncthreads();
#pragma unroll
    for (int i = 0; i < 12; ++i) {
        int t = wave + i * 4;
        int rtL = t & 1, ct = t >> 1;
        int col = ct * 16 + mcol;
        int hh = col >> 6, nn = col & 63;
        int d0 = rtL * 16 + (g << 2);
        *(ushort4*)(&sYF[nn * 200 + hh * 32 + d0]) = w4st[i];
    }
    __syncthreads();

    // out = finalX @ pw^T + pb ; ct-major: each wave owns 3 col-tiles, pw frags
    // register-resident per ct
    {
        float* outp = out + (size_t)b * 12288;
#pragma unroll
        for (int q = 0; q < 3; ++q) {
            int ct = wave * 3 + q;
            bf16x8 wfp[6];
#pragma unroll
            for (int ks = 0; ks < 6; ++ks) wfp[ks] = frag(pwbf, DIM, ct * 16, ks * 32);
            int co = ct * 16 + mcol;
            float pbv = pb[co];
#pragma unroll
            for (int rt = 0; rt < 4; ++rt) {
                f32x4 acc = zero4;
#pragma unroll
                for (int ks = 0; ks < 6; ++ks)
                    acc = MF(frag(sYF, 200, rt * 16, ks * 32), wfp[ks], acc);
#pragma unroll
                for (int j = 0; j < 4; ++j)
                    outp[(rt * 16 + (g << 2) + j) * DIM + co] = acc[j] + pbv;
            }
        }
    }
}

extern "C" void kernel_launch(void* const* d_in, const int* in_sizes, int n_in,
                              void* d_out, int out_size, void* d_ws, size_t ws_size,
                              hipStream_t stream) {
    const float* x1    = (const float*)d_in[0];
    const float* x2    = (const float*)d_in[1];
    const float* mask  = (const float*)d_in[2];
    const float* qw    = (const float*)d_in[3];
    const float* qbv   = (const float*)d_in[4];
    const float* kvw   = (const float*)d_in[5];
    const float* kvbv  = (const float*)d_in[6];
    const float* rpb   = (const float*)d_in[7];
    const float* gamma = (const float*)d_in[8];
    const float* pw    = (const float*)d_in[9];
    const float* pbv   = (const float*)d_in[10];
    ushort* wbf = (ushort*)d_ws;     // qw_bf | kvw_bf | pw_bf

    ushort* cmb = wbf + 147456;      // 3 MB bias+mask table
    ushort* Qf  = wbf + 1720320;     // fragment-linear q̂ (pre-scaled)
    ushort* Kf  = wbf + 26886144;    // fragment-linear K; becomes Y after attn
    ushort* Vf  = wbf + 52051968;    // fragment-linear V

    prep_all<<<2112, 256, 0, stream>>>(qw, kvw, pw, rpb, mask, wbf, cmb);
    proj7<<<2048, 256, 0, stream>>>(x1, x2, qbv, kvbv,
                                    wbf, wbf + 36864, Qf, Kf, Vf);
    attn_heads<<<3072, 256, 0, stream>>>(Qf, Kf, Vf, cmb);
    lam_proj<<<2048, 256, 0, stream>>>(Kf, Qf, x1, gamma,
                                       wbf + 110592, pbv, (float*)d_out);
}